// Round 4
// baseline (145.690 us; speedup 1.0000x reference)
//
#include <hip/hip_runtime.h>
#include <math.h>

typedef __attribute__((ext_vector_type(8))) short bf16x8;
typedef __attribute__((ext_vector_type(4))) short bf16x4;
typedef __attribute__((ext_vector_type(4))) float f32x4;

#define BB    4
#define SEQ   1024
#define DIMV  512
#define TD    1536
#define NH    8
#define DH    128
#define MROWS (BB*SEQ)

__device__ inline unsigned short f2bf(float x){
    union { float f; unsigned u; } v; v.f = x;
    unsigned r = v.u + 0x7FFF + ((v.u >> 16) & 1);   // RNE
    return (unsigned short)(r >> 16);
}
__device__ inline float bf2f(unsigned short h){
    union { unsigned u; float f; } v; v.u = ((unsigned)h) << 16; return v.f;
}

__device__ inline void glds16(const void* g, void* l){
    __builtin_amdgcn_global_load_lds(
        (const __attribute__((address_space(1))) unsigned int*)g,
        (__attribute__((address_space(3))) unsigned int*)l,
        16, 0, 0);
}

// ---------------- Prep A: split x|a into hi/lo bf16, K-granule-major ----------------
__global__ __launch_bounds__(256) void prep_a(
    const float* __restrict__ X, const float* __restrict__ A,
    unsigned short* __restrict__ Ahi, unsigned short* __restrict__ Alo)
{
    const int m   = blockIdx.x*256 + threadIdx.x;
    const int pg  = blockIdx.y;         // p*4+g  (0..63)
    const int mat = blockIdx.z;
    const float* In = mat ? A : X;
    const float* src = In + (size_t)m*DIMV + pg*8;
    float4 v0 = *(const float4*)src;
    float4 v1 = *(const float4*)(src+4);
    float v[8] = {v0.x,v0.y,v0.z,v0.w,v1.x,v1.y,v1.z,v1.w};
    bf16x8 h, l;
    #pragma unroll
    for (int j=0;j<8;++j){
        unsigned short hb = f2bf(v[j]);
        h[j] = (short)hb;
        l[j] = (short)f2bf(v[j] - bf2f(hb));
    }
    const size_t o = ((size_t)(mat*64 + pg)*4096 + m)*8;
    *(bf16x8*)(Ahi+o) = h;
    *(bf16x8*)(Alo+o) = l;
}

// ---------------- Prep B: transpose+split W into hi/lo bf16, K-granule-major ----------
__global__ __launch_bounds__(256) void prep_b(
    const float* __restrict__ Wx, const float* __restrict__ Wa,
    unsigned short* __restrict__ Bhi, unsigned short* __restrict__ Blo)
{
    const int n   = blockIdx.x*256 + threadIdx.x;
    const int pg  = blockIdx.y;
    const int mat = blockIdx.z;
    const float* W = mat ? Wa : Wx;
    bf16x8 h, l;
    #pragma unroll
    for (int j=0;j<8;++j){
        float v = W[(size_t)(pg*8 + j)*TD + n];
        unsigned short hb = f2bf(v);
        h[j] = (short)hb;
        l[j] = (short)f2bf(v - bf2f(hb));
    }
    const size_t o = ((size_t)(mat*64 + pg)*1536 + n)*8;
    *(bf16x8*)(Bhi+o) = h;
    *(bf16x8*)(Blo+o) = l;
}

// ---------------- Kernel 1: QKV GEMM via bf16 MFMA, hi/lo 3-pass ----------------
__global__ __launch_bounds__(256,3) void qkv_mfma(
    const unsigned short* __restrict__ Ahi, const unsigned short* __restrict__ Alo,
    const unsigned short* __restrict__ Bhi, const unsigned short* __restrict__ Blo,
    float* __restrict__ wsq, float* __restrict__ wsk,
    unsigned short* __restrict__ Vt)
{
    __shared__ __align__(16) unsigned short sAh[4096];
    __shared__ __align__(16) unsigned short sAl[4096];
    __shared__ __align__(16) unsigned short sBh[4096];
    __shared__ __align__(16) unsigned short sBl[4096];

    const int mat = blockIdx.z;
    const int bm  = blockIdx.x * 128;
    const int bn  = blockIdx.y * 128;
    const int tid = threadIdx.x;
    const int w   = tid >> 6, l = tid & 63;
    const int wr  = w >> 1,  wc = w & 1;
    const int lg  = l >> 4,  ln = l & 15;

    f32x4 acc[4][4];
    #pragma unroll
    for (int i=0;i<4;++i)
        #pragma unroll
        for (int j=0;j<4;++j){ acc[i][j][0]=0.f; acc[i][j][1]=0.f; acc[i][j][2]=0.f; acc[i][j][3]=0.f; }

    const int g0 = tid >> 7, r0 = tid & 127;
    const size_t ASTEP = (size_t)4*4096*8;
    const size_t BSTEP = (size_t)4*1536*8;
    const unsigned short* a0h = Ahi + ((size_t)(mat*64 + g0)*4096 + bm + r0)*8;
    const unsigned short* a0l = Alo + ((size_t)(mat*64 + g0)*4096 + bm + r0)*8;
    const unsigned short* a1h = a0h + (size_t)2*4096*8;
    const unsigned short* a1l = a0l + (size_t)2*4096*8;
    const unsigned short* b0h = Bhi + ((size_t)(mat*64 + g0)*1536 + bn + r0)*8;
    const unsigned short* b0l = Blo + ((size_t)(mat*64 + g0)*1536 + bn + r0)*8;
    const unsigned short* b1h = b0h + (size_t)2*1536*8;
    const unsigned short* b1l = b0l + (size_t)2*1536*8;

    const int d0 = w*512, d1 = 2048 + w*512;

    for (int p=0; p<16; ++p){
        glds16(a0h, sAh + d0);  glds16(a1h, sAh + d1);
        glds16(a0l, sAl + d0);  glds16(a1l, sAl + d1);
        glds16(b0h, sBh + d0);  glds16(b1h, sBh + d1);
        glds16(b0l, sBl + d0);  glds16(b1l, sBl + d1);
        a0h += ASTEP; a1h += ASTEP; a0l += ASTEP; a1l += ASTEP;
        b0h += BSTEP; b1h += BSTEP; b0l += BSTEP; b1l += BSTEP;
        __syncthreads();

        bf16x8 ah[4], al[4], bh[4], bl[4];
        #pragma unroll
        for (int mi=0; mi<4; ++mi){
            const int off = (lg*128 + wr*64 + mi*16 + ln)*8;
            ah[mi] = *(const bf16x8*)(sAh + off);
            al[mi] = *(const bf16x8*)(sAl + off);
        }
        #pragma unroll
        for (int ni=0; ni<4; ++ni){
            const int off = (lg*128 + wc*64 + ni*16 + ln)*8;
            bh[ni] = *(const bf16x8*)(sBh + off);
            bl[ni] = *(const bf16x8*)(sBl + off);
        }
        #pragma unroll
        for (int mi=0; mi<4; ++mi)
            #pragma unroll
            for (int ni=0; ni<4; ++ni){
                acc[mi][ni] = __builtin_amdgcn_mfma_f32_16x16x32_bf16(ah[mi], bh[ni], acc[mi][ni], 0,0,0);
                acc[mi][ni] = __builtin_amdgcn_mfma_f32_16x16x32_bf16(ah[mi], bl[ni], acc[mi][ni], 0,0,0);
                acc[mi][ni] = __builtin_amdgcn_mfma_f32_16x16x32_bf16(al[mi], bh[ni], acc[mi][ni], 0,0,0);
            }
        __syncthreads();
    }

    const int b_ = bm >> 10;
    const int n0base = (bm & 1023) + wr*64;
    const int colB = bn + wc*64;
    if (colB < 1024){
        float* base = (colB < 512) ? wsq : wsk;
        #pragma unroll
        for (int ni=0; ni<4; ++ni){
            const int col = colB + ni*16 + ln;
            const int h = mat*4 + ((col >> 7) & 3);
            const int d = col & 127;
            #pragma unroll
            for (int mi=0; mi<4; ++mi){
                const int n0 = n0base + mi*16 + lg*4;
                float* dst = base + ((size_t)(b_*NH + h)*SEQ + n0)*DH + d;
                #pragma unroll
                for (int r=0;r<4;++r) dst[r*DH] = acc[mi][ni][r];
            }
        }
    } else {
        #pragma unroll
        for (int ni=0; ni<4; ++ni){
            const int col = colB + ni*16 + ln;
            const int h = mat*4 + ((col >> 7) & 3);
            const int d = col & 127;
            #pragma unroll
            for (int mi=0; mi<4; ++mi){
                const int n0 = n0base + mi*16 + lg*4;
                unsigned short* dst = Vt + ((size_t)(b_*NH + h)*DH + d)*SEQ + n0;
                bf16x4 pk;
                #pragma unroll
                for (int r=0;r<4;++r) pk[r] = (short)f2bf(acc[mi][ni][r]);
                *(bf16x4*)dst = pk;
            }
        }
    }
}

// ---------------- Kernel 2: LayerNorm + RoPE -> bf16 ----------------
__global__ __launch_bounds__(512) void ln_rope(
    const float* __restrict__ wsq, const float* __restrict__ wsk,
    unsigned short* __restrict__ Qb, unsigned short* __restrict__ Kb,
    const float* __restrict__ g_qx, const float* __restrict__ b_qx,
    const float* __restrict__ g_kx, const float* __restrict__ b_kx,
    const float* __restrict__ g_qa, const float* __restrict__ b_qa,
    const float* __restrict__ g_ka, const float* __restrict__ b_ka)
{
    __shared__ float red[16];
    __shared__ float vn[512];
    const int r = blockIdx.x;
    const int which = blockIdx.y;
    const int b_ = r >> 10;
    const int n_ = r & 1023;
    const float* buf = (which & 1) ? wsk : wsq;
    unsigned short* ob = (which & 1) ? Kb : Qb;
    const int h0 = (which >> 1) ? 4 : 0;
    const float* g; const float* bb;
    if (which==0){ g=g_qx; bb=b_qx; }
    else if (which==1){ g=g_kx; bb=b_kx; }
    else if (which==2){ g=g_qa; bb=b_qa; }
    else { g=g_ka; bb=b_ka; }

    const int t = threadIdx.x;
    const int h = h0 + (t >> 7);
    const int d = t & 127;
    const size_t idx = ((size_t)(b_*NH + h)*SEQ + n_)*DH + d;
    float v = buf[idx];
    float s1 = v, s2 = v*v;
    #pragma unroll
    for (int o=32;o>=1;o>>=1){
        s1 += __shfl_down(s1,o);
        s2 += __shfl_down(s2,o);
    }
    const int lane = t & 63, wv = t >> 6;
    if (lane==0){ red[wv]=s1; red[8+wv]=s2; }
    __syncthreads();
    float sum=0.f, sq=0.f;
    #pragma unroll
    for (int w=0;w<8;++w){ sum+=red[w]; sq+=red[8+w]; }
    const float mu = sum * (1.f/512.f);
    const float var = sq * (1.f/512.f) - mu*mu;
    const float rs = rsqrtf(var + 1e-5f);
    const float xn = (v - mu)*rs*g[t] + bb[t];
    vn[t] = xn;
    __syncthreads();
    const float partner = vn[t ^ 64];
    const int dd = d & 63;
    const float fr = (float)dd * (1.f/64.f);
    const float inv = expf(fr * -9.210340371976184f);
    const float ang = (float)n_ * inv;
    float sn, cs;
    sincosf(ang, &sn, &cs);
    const float rot = (d < 64) ? -partner : partner;
    float val = xn*cs + rot*sn;
    // fold 1/sqrt(128) * log2(e) into Q (softmax runs in exp2 domain)
    if (!(which & 1)) val *= 0.08838834764831845f * 1.4426950408889634f;
    ob[idx] = f2bf(val);
}

// ---------------- Kernel 3: MFMA flash attention (bf16) ----------------
// 4 waves x 16 q-rows. K double-buffered in LDS via direct global_load_lds
// (pre-swizzled source, linear dest). V read global->reg (L2-resident),
// issued early, consumed after S+softmax. P per-wave LDS. One barrier/iter.
__global__ __launch_bounds__(256,2) void attn_mfma(
    const unsigned short* __restrict__ Qb, const unsigned short* __restrict__ Kb,
    const unsigned short* __restrict__ Vt, float* __restrict__ out)
{
    __shared__ __align__(16) unsigned short Ks[2][64*128];  // 2 x 16KB
    __shared__ __align__(16) unsigned short Ps[4*16*64];    // 8KB

    const int bh = blockIdx.y;
    const int q0 = blockIdx.x * 64;
    const int tid = threadIdx.x;
    const int w  = tid >> 6;
    const int l  = tid & 63;
    const int lg = l >> 4;
    const int ln = l & 15;
    const size_t hoff = (size_t)bh * SEQ * DH;

    bf16x8 qf[4];
    {
        const unsigned short* qp = Qb + hoff + (size_t)(q0 + w*16 + ln)*DH + lg*8;
        #pragma unroll
        for (int c=0;c<4;++c) qf[c] = *(const bf16x8*)(qp + c*32);
    }

    f32x4 o[8];
    #pragma unroll
    for (int dt=0;dt<8;++dt){ o[dt][0]=0.f; o[dt][1]=0.f; o[dt][2]=0.f; o[dt][3]=0.f; }
    float mrun[4] = {-INFINITY,-INFINITY,-INFINITY,-INFINITY};
    float lrun[4] = {0.f,0.f,0.f,0.f};

    const unsigned short* kg0 = Kb + hoff;
    const unsigned short* vg0 = Vt + hoff;
    unsigned short* Pw = Ps + w*1024;
    const int lnsw = ln & 7;

    // stage K tile kt into buffer bb: LDS linear, source pre-swizzled (inverse XOR)
    #define STAGE_K(bb, kt) { \
        const unsigned short* kg_ = kg0 + (size_t)(kt)*64*128; \
        _Pragma("unroll") \
        for (int i_=0;i_<4;++i_){ \
            int f_ = tid + i_*256; \
            int r_ = f_ >> 4, s_ = f_ & 15; \
            glds16(kg_ + r_*128 + ((s_ ^ (r_&7))*8), (unsigned short*)Ks[bb] + f_*8); \
        } }

    STAGE_K(0, 0);
    asm volatile("s_waitcnt vmcnt(0)" ::: "memory");
    __builtin_amdgcn_s_barrier();

    int cur = 0;
    for (int kt=0; kt<SEQ/64; ++kt){
        // issue next K-tile loads first (fly under compute)
        if (kt < SEQ/64 - 1) STAGE_K(cur^1, kt+1);

        // issue V fragments for current tile (global->reg, L2 hits)
        bf16x8 vf[2][8];
        #pragma unroll
        for (int kc=0;kc<2;++kc)
            #pragma unroll
            for (int dt=0;dt<8;++dt)
                vf[kc][dt] = *(const bf16x8*)(vg0 + (size_t)(dt*16+ln)*SEQ
                                              + kt*64 + ((kc<<2)|lg)*8);

        // ---- S = Q K^T ----
        f32x4 s[4];
        #pragma unroll
        for (int ct=0;ct<4;++ct){ s[ct][0]=0.f; s[ct][1]=0.f; s[ct][2]=0.f; s[ct][3]=0.f; }
        __builtin_amdgcn_s_setprio(1);
        #pragma unroll
        for (int ct=0; ct<4; ++ct){
            const int kr = ct*16 + ln;
            const unsigned short* kb = Ks[cur] + kr*128;
            const int sw = kr & 7;
            #pragma unroll
            for (int c=0;c<4;++c){
                bf16x8 kf = *(const bf16x8*)(kb + ((((c<<2)|lg) ^ sw)*8));
                s[ct] = __builtin_amdgcn_mfma_f32_16x16x32_bf16(qf[c], kf, s[ct], 0,0,0);
            }
        }
        __builtin_amdgcn_s_setprio(0);

        // ---- online softmax in exp2 domain ----
        float mx[4];
        #pragma unroll
        for (int r=0;r<4;++r){
            float m_ = fmaxf(fmaxf(s[0][r], s[1][r]), fmaxf(s[2][r], s[3][r]));
            m_ = fmaxf(m_, __shfl_xor(m_,1));
            m_ = fmaxf(m_, __shfl_xor(m_,2));
            m_ = fmaxf(m_, __shfl_xor(m_,4));
            m_ = fmaxf(m_, __shfl_xor(m_,8));
            mx[r] = m_;
        }
        bool grow = false;
        #pragma unroll
        for (int r=0;r<4;++r) grow = grow || (mx[r] > mrun[r] + 8.f);
        if (__any(grow)){
            float al[4];
            #pragma unroll
            for (int r=0;r<4;++r){
                const float mn = fmaxf(mrun[r], mx[r]);
                al[r] = __builtin_amdgcn_exp2f(mrun[r]-mn);
                mrun[r] = mn;
                lrun[r] *= al[r];
            }
            #pragma unroll
            for (int dt=0;dt<8;++dt){
                o[dt][0]*=al[0]; o[dt][1]*=al[1]; o[dt][2]*=al[2]; o[dt][3]*=al[3];
            }
        }
        float pv[4][4];
        #pragma unroll
        for (int r=0;r<4;++r){
            float sum = 0.f;
            #pragma unroll
            for (int ct=0;ct<4;++ct){
                float p = __builtin_amdgcn_exp2f(s[ct][r]-mrun[r]);
                pv[r][ct] = p; sum += p;
            }
            sum += __shfl_xor(sum,1);
            sum += __shfl_xor(sum,2);
            sum += __shfl_xor(sum,4);
            sum += __shfl_xor(sum,8);
            lrun[r] += sum;
        }

        // ---- write P (bf16, per-wave swizzled LDS) ----
        #pragma unroll
        for (int r=0;r<4;++r){
            const int m = lg*4 + r;
            unsigned short* pr = Pw + m*64;
            const int sw = m & 7;
            #pragma unroll
            for (int ct=0;ct<4;++ct){
                int col = ct*16 + ln;
                pr[(((col>>3) ^ sw)*8) + (col&7)] = f2bf(pv[r][ct]);
            }
        }

        // ---- O += P V (V from registers) ----
        __builtin_amdgcn_s_setprio(1);
        #pragma unroll
        for (int kc=0;kc<2;++kc){
            bf16x8 pf = *(const bf16x8*)(Pw + ln*64 + ((((kc<<2)|lg) ^ lnsw)*8));
            #pragma unroll
            for (int dt=0;dt<8;++dt)
                o[dt] = __builtin_amdgcn_mfma_f32_16x16x32_bf16(pf, vf[kc][dt], o[dt], 0,0,0);
        }
        __builtin_amdgcn_s_setprio(0);

        if (kt < SEQ/64 - 1){
            asm volatile("s_waitcnt vmcnt(0)" ::: "memory");
            __builtin_amdgcn_s_barrier();
            cur ^= 1;
        }
    }
    #undef STAGE_K

    const int b_ = bh >> 3, h_ = bh & 7;
    #pragma unroll
    for (int r=0;r<4;++r){
        const float inv = 1.0f / lrun[r];
        const int n_ = q0 + w*16 + lg*4 + r;
        float* op = out + ((size_t)(b_*SEQ) + n_)*1024 + h_*128 + ln;
        #pragma unroll
        for (int dt=0;dt<8;++dt)
            op[dt*16] = o[dt][r] * inv;
    }
}

extern "C" void kernel_launch(void* const* d_in, const int* in_sizes, int n_in,
                              void* d_out, int out_size, void* d_ws, size_t ws_size,
                              hipStream_t stream) {
    const float* x    = (const float*)d_in[0];
    const float* a    = (const float*)d_in[1];
    const float* Wx   = (const float*)d_in[2];
    const float* Wa   = (const float*)d_in[3];
    const float* g_qx = (const float*)d_in[4];
    const float* b_qx = (const float*)d_in[5];
    const float* g_kx = (const float*)d_in[6];
    const float* b_kx = (const float*)d_in[7];
    const float* g_qa = (const float*)d_in[8];
    const float* b_qa = (const float*)d_in[9];
    const float* g_ka = (const float*)d_in[10];
    const float* b_ka = (const float*)d_in[11];
    float* out = (float*)d_out;

    const size_t E = (size_t)BB*NH*SEQ*DH;        // 4,194,304 elements
    float* wsq = (float*)d_ws;                    // 16MB
    float* wsk = wsq + E;                         // 16MB
    unsigned short* Vt = (unsigned short*)(wsk + E);  // 8MB
    unsigned short* region = Vt + E;              // dual-use
    unsigned short* Ahi = region;                 // 8MB (gemm phase)
    unsigned short* Alo = region + E;             // 8MB
    unsigned short* Qb  = region;                 // 8MB (attn phase)
    unsigned short* Kb  = region + E;             // 8MB
    unsigned short* Bhi = region + 2*E;           // 3MB
    unsigned short* Blo = Bhi + (size_t)2*64*1536*8;  // 3MB

    prep_a<<<dim3(16, 64, 2), 256, 0, stream>>>(x, a, Ahi, Alo);
    prep_b<<<dim3(6, 64, 2), 256, 0, stream>>>(Wx, Wa, Bhi, Blo);
    qkv_mfma<<<dim3(32, 12, 2), 256, 0, stream>>>(Ahi, Alo, Bhi, Blo, wsq, wsk, Vt);
    ln_rope<<<dim3(MROWS, 4), 512, 0, stream>>>(wsq, wsk, Qb, Kb,
        g_qx, b_qx, g_kx, b_kx, g_qa, b_qa, g_ka, b_ka);
    attn_mfma<<<dim3(SEQ/64, BB*NH), 256, 0, stream>>>(Qb, Kb, Vt, out);
}

// Round 5
// 125.945 us; speedup vs baseline: 1.1568x; 1.1568x over previous
//
#include <hip/hip_runtime.h>
#include <math.h>

typedef __attribute__((ext_vector_type(8))) short bf16x8;
typedef __attribute__((ext_vector_type(4))) short bf16x4;
typedef __attribute__((ext_vector_type(4))) float f32x4;

#define BB    4
#define SEQ   1024
#define DIMV  512
#define TD    1536
#define NH    8
#define DH    128
#define MROWS (BB*SEQ)

__device__ inline unsigned short f2bf(float x){
    union { float f; unsigned u; } v; v.f = x;
    unsigned r = v.u + 0x7FFF + ((v.u >> 16) & 1);   // RNE
    return (unsigned short)(r >> 16);
}
__device__ inline float bf2f(unsigned short h){
    union { unsigned u; float f; } v; v.u = ((unsigned)h) << 16; return v.f;
}

__device__ inline void glds16(const void* g, void* l){
    __builtin_amdgcn_global_load_lds(
        (const __attribute__((address_space(1))) unsigned int*)g,
        (__attribute__((address_space(3))) unsigned int*)l,
        16, 0, 0);
}

// ---------------- Prep A: split x|a into hi/lo bf16, K-granule-major ----------------
__global__ __launch_bounds__(256) void prep_a(
    const float* __restrict__ X, const float* __restrict__ A,
    unsigned short* __restrict__ Ahi, unsigned short* __restrict__ Alo)
{
    const int m   = blockIdx.x*256 + threadIdx.x;
    const int pg  = blockIdx.y;         // p*4+g  (0..63)
    const int mat = blockIdx.z;
    const float* In = mat ? A : X;
    const float* src = In + (size_t)m*DIMV + pg*8;
    float4 v0 = *(const float4*)src;
    float4 v1 = *(const float4*)(src+4);
    float v[8] = {v0.x,v0.y,v0.z,v0.w,v1.x,v1.y,v1.z,v1.w};
    bf16x8 h, l;
    #pragma unroll
    for (int j=0;j<8;++j){
        unsigned short hb = f2bf(v[j]);
        h[j] = (short)hb;
        l[j] = (short)f2bf(v[j] - bf2f(hb));
    }
    const size_t o = ((size_t)(mat*64 + pg)*4096 + m)*8;
    *(bf16x8*)(Ahi+o) = h;
    *(bf16x8*)(Alo+o) = l;
}

// ---------------- Prep B: transpose+split W into hi/lo bf16, K-granule-major ----------
__global__ __launch_bounds__(256) void prep_b(
    const float* __restrict__ Wx, const float* __restrict__ Wa,
    unsigned short* __restrict__ Bhi, unsigned short* __restrict__ Blo)
{
    const int n   = blockIdx.x*256 + threadIdx.x;
    const int pg  = blockIdx.y;
    const int mat = blockIdx.z;
    const float* W = mat ? Wa : Wx;
    bf16x8 h, l;
    #pragma unroll
    for (int j=0;j<8;++j){
        float v = W[(size_t)(pg*8 + j)*TD + n];
        unsigned short hb = f2bf(v);
        h[j] = (short)hb;
        l[j] = (short)f2bf(v - bf2f(hb));
    }
    const size_t o = ((size_t)(mat*64 + pg)*1536 + n)*8;
    *(bf16x8*)(Bhi+o) = h;
    *(bf16x8*)(Blo+o) = l;
}

// ---------------- Kernel 1: QKV GEMM via bf16 MFMA, hi/lo 3-pass ----------------
__global__ __launch_bounds__(256,3) void qkv_mfma(
    const unsigned short* __restrict__ Ahi, const unsigned short* __restrict__ Alo,
    const unsigned short* __restrict__ Bhi, const unsigned short* __restrict__ Blo,
    float* __restrict__ wsq, float* __restrict__ wsk,
    unsigned short* __restrict__ Vt)
{
    __shared__ __align__(16) unsigned short sAh[4096];
    __shared__ __align__(16) unsigned short sAl[4096];
    __shared__ __align__(16) unsigned short sBh[4096];
    __shared__ __align__(16) unsigned short sBl[4096];

    const int mat = blockIdx.z;
    const int bm  = blockIdx.x * 128;
    const int bn  = blockIdx.y * 128;
    const int tid = threadIdx.x;
    const int w   = tid >> 6, l = tid & 63;
    const int wr  = w >> 1,  wc = w & 1;
    const int lg  = l >> 4,  ln = l & 15;

    f32x4 acc[4][4];
    #pragma unroll
    for (int i=0;i<4;++i)
        #pragma unroll
        for (int j=0;j<4;++j){ acc[i][j][0]=0.f; acc[i][j][1]=0.f; acc[i][j][2]=0.f; acc[i][j][3]=0.f; }

    const int g0 = tid >> 7, r0 = tid & 127;
    const size_t ASTEP = (size_t)4*4096*8;
    const size_t BSTEP = (size_t)4*1536*8;
    const unsigned short* a0h = Ahi + ((size_t)(mat*64 + g0)*4096 + bm + r0)*8;
    const unsigned short* a0l = Alo + ((size_t)(mat*64 + g0)*4096 + bm + r0)*8;
    const unsigned short* a1h = a0h + (size_t)2*4096*8;
    const unsigned short* a1l = a0l + (size_t)2*4096*8;
    const unsigned short* b0h = Bhi + ((size_t)(mat*64 + g0)*1536 + bn + r0)*8;
    const unsigned short* b0l = Blo + ((size_t)(mat*64 + g0)*1536 + bn + r0)*8;
    const unsigned short* b1h = b0h + (size_t)2*1536*8;
    const unsigned short* b1l = b0l + (size_t)2*1536*8;

    const int d0 = w*512, d1 = 2048 + w*512;

    for (int p=0; p<16; ++p){
        glds16(a0h, sAh + d0);  glds16(a1h, sAh + d1);
        glds16(a0l, sAl + d0);  glds16(a1l, sAl + d1);
        glds16(b0h, sBh + d0);  glds16(b1h, sBh + d1);
        glds16(b0l, sBl + d0);  glds16(b1l, sBl + d1);
        a0h += ASTEP; a1h += ASTEP; a0l += ASTEP; a1l += ASTEP;
        b0h += BSTEP; b1h += BSTEP; b0l += BSTEP; b1l += BSTEP;
        __syncthreads();

        bf16x8 ah[4], al[4], bh[4], bl[4];
        #pragma unroll
        for (int mi=0; mi<4; ++mi){
            const int off = (lg*128 + wr*64 + mi*16 + ln)*8;
            ah[mi] = *(const bf16x8*)(sAh + off);
            al[mi] = *(const bf16x8*)(sAl + off);
        }
        #pragma unroll
        for (int ni=0; ni<4; ++ni){
            const int off = (lg*128 + wc*64 + ni*16 + ln)*8;
            bh[ni] = *(const bf16x8*)(sBh + off);
            bl[ni] = *(const bf16x8*)(sBl + off);
        }
        #pragma unroll
        for (int mi=0; mi<4; ++mi)
            #pragma unroll
            for (int ni=0; ni<4; ++ni){
                acc[mi][ni] = __builtin_amdgcn_mfma_f32_16x16x32_bf16(ah[mi], bh[ni], acc[mi][ni], 0,0,0);
                acc[mi][ni] = __builtin_amdgcn_mfma_f32_16x16x32_bf16(ah[mi], bl[ni], acc[mi][ni], 0,0,0);
                acc[mi][ni] = __builtin_amdgcn_mfma_f32_16x16x32_bf16(al[mi], bh[ni], acc[mi][ni], 0,0,0);
            }
        __syncthreads();
    }

    const int b_ = bm >> 10;
    const int n0base = (bm & 1023) + wr*64;
    const int colB = bn + wc*64;
    if (colB < 1024){
        float* base = (colB < 512) ? wsq : wsk;
        #pragma unroll
        for (int ni=0; ni<4; ++ni){
            const int col = colB + ni*16 + ln;
            const int h = mat*4 + ((col >> 7) & 3);
            const int d = col & 127;
            #pragma unroll
            for (int mi=0; mi<4; ++mi){
                const int n0 = n0base + mi*16 + lg*4;
                float* dst = base + ((size_t)(b_*NH + h)*SEQ + n0)*DH + d;
                #pragma unroll
                for (int r=0;r<4;++r) dst[r*DH] = acc[mi][ni][r];
            }
        }
    } else {
        #pragma unroll
        for (int ni=0; ni<4; ++ni){
            const int col = colB + ni*16 + ln;
            const int h = mat*4 + ((col >> 7) & 3);
            const int d = col & 127;
            #pragma unroll
            for (int mi=0; mi<4; ++mi){
                const int n0 = n0base + mi*16 + lg*4;
                unsigned short* dst = Vt + ((size_t)(b_*NH + h)*DH + d)*SEQ + n0;
                bf16x4 pk;
                #pragma unroll
                for (int r=0;r<4;++r) pk[r] = (short)f2bf(acc[mi][ni][r]);
                *(bf16x4*)dst = pk;
            }
        }
    }
}

// ---------------- RoPE cos/sin table: tab[n*64+dd] = (cos, sin)(n * 10000^{-dd/64}) ----
__global__ __launch_bounds__(256) void rope_tab(float2* __restrict__ tab)
{
    const int i = blockIdx.x*256 + threadIdx.x;   // 65536
    const int n = i >> 6, dd = i & 63;
    const float inv = expf((float)dd * (1.f/64.f) * -9.210340371976184f);
    const float ang = (float)n * inv;
    float sn, cs;
    sincosf(ang, &sn, &cs);
    tab[i] = make_float2(cs, sn);
}

// ---------------- Kernel 2: LayerNorm + RoPE -> bf16 ----------------
__global__ __launch_bounds__(512) void ln_rope(
    const float* __restrict__ wsq, const float* __restrict__ wsk,
    unsigned short* __restrict__ Qb, unsigned short* __restrict__ Kb,
    const float2* __restrict__ tab,
    const float* __restrict__ g_qx, const float* __restrict__ b_qx,
    const float* __restrict__ g_kx, const float* __restrict__ b_kx,
    const float* __restrict__ g_qa, const float* __restrict__ b_qa,
    const float* __restrict__ g_ka, const float* __restrict__ b_ka)
{
    __shared__ float red[16];
    __shared__ float vn[512];
    const int r = blockIdx.x;
    const int which = blockIdx.y;
    const int b_ = r >> 10;
    const int n_ = r & 1023;
    const float* buf = (which & 1) ? wsk : wsq;
    unsigned short* ob = (which & 1) ? Kb : Qb;
    const int h0 = (which >> 1) ? 4 : 0;
    const float* g; const float* bb;
    if (which==0){ g=g_qx; bb=b_qx; }
    else if (which==1){ g=g_kx; bb=b_kx; }
    else if (which==2){ g=g_qa; bb=b_qa; }
    else { g=g_ka; bb=b_ka; }

    const int t = threadIdx.x;
    const int h = h0 + (t >> 7);
    const int d = t & 127;
    const size_t idx = ((size_t)(b_*NH + h)*SEQ + n_)*DH + d;
    float v = buf[idx];
    float s1 = v, s2 = v*v;
    #pragma unroll
    for (int o=32;o>=1;o>>=1){
        s1 += __shfl_down(s1,o);
        s2 += __shfl_down(s2,o);
    }
    const int lane = t & 63, wv = t >> 6;
    if (lane==0){ red[wv]=s1; red[8+wv]=s2; }
    __syncthreads();
    float sum=0.f, sq=0.f;
    #pragma unroll
    for (int w=0;w<8;++w){ sum+=red[w]; sq+=red[8+w]; }
    const float mu = sum * (1.f/512.f);
    const float var = sq * (1.f/512.f) - mu*mu;
    const float rs = rsqrtf(var + 1e-5f);
    const float xn = (v - mu)*rs*g[t] + bb[t];
    vn[t] = xn;
    __syncthreads();
    const float partner = vn[t ^ 64];
    const float2 cssn = tab[(n_ << 6) + (d & 63)];
    const float rot = (d < 64) ? -partner : partner;
    float val = xn*cssn.x + rot*cssn.y;
    // fold 1/sqrt(128) * log2(e) into Q (softmax runs in exp2 domain)
    if (!(which & 1)) val *= 0.08838834764831845f * 1.4426950408889634f;
    ob[idx] = f2bf(val);
}

// ---------------- Kernel 3: MFMA flash attention (bf16) ----------------
// 4 waves x 16 q-rows. K AND V cooperatively staged via global_load_lds
// (pre-swizzled per-lane source, linear LDS dest), double-buffered;
// prefetch issued before compute; one vmcnt(0)+barrier per iteration.
__global__ __launch_bounds__(256,2) void attn_mfma(
    const unsigned short* __restrict__ Qb, const unsigned short* __restrict__ Kb,
    const unsigned short* __restrict__ Vt, float* __restrict__ out)
{
    __shared__ __align__(16) unsigned short Ks[2][64*128];  // 2 x 16KB
    __shared__ __align__(16) unsigned short Vs[2][128*64];  // 2 x 16KB (V^T)
    __shared__ __align__(16) unsigned short Ps[4*16*64];    // 8KB

    const int bh = blockIdx.y;
    const int q0 = blockIdx.x * 64;
    const int tid = threadIdx.x;
    const int w  = tid >> 6;
    const int l  = tid & 63;
    const int lg = l >> 4;
    const int ln = l & 15;
    const size_t hoff = (size_t)bh * SEQ * DH;

    bf16x8 qf[4];
    {
        const unsigned short* qp = Qb + hoff + (size_t)(q0 + w*16 + ln)*DH + lg*8;
        #pragma unroll
        for (int c=0;c<4;++c) qf[c] = *(const bf16x8*)(qp + c*32);
    }

    f32x4 o[8];
    #pragma unroll
    for (int dt=0;dt<8;++dt){ o[dt][0]=0.f; o[dt][1]=0.f; o[dt][2]=0.f; o[dt][3]=0.f; }
    float mrun[4] = {-INFINITY,-INFINITY,-INFINITY,-INFINITY};
    float lrun[4] = {0.f,0.f,0.f,0.f};

    const unsigned short* kg0 = Kb + hoff;
    const unsigned short* vg0 = Vt + hoff;
    unsigned short* Pw = Ps + w*1024;
    const int lnsw = ln & 7;

    // Stage K (64x128) and V^T (128x64) tiles: LDS dest linear in granule id,
    // global source carries the inverse XOR swizzle (T21 both-sides rule).
    #define STAGE_KV(bb, kt) { \
        const unsigned short* kg_ = kg0 + (size_t)(kt)*64*128; \
        _Pragma("unroll") \
        for (int i_=0;i_<4;++i_){ \
            int f_ = tid + i_*256; \
            int r_ = f_ >> 4, s_ = f_ & 15; \
            glds16(kg_ + r_*128 + ((s_ ^ (r_&7))*8), (unsigned short*)Ks[bb] + f_*8); \
        } \
        _Pragma("unroll") \
        for (int i_=0;i_<4;++i_){ \
            int f_ = tid + i_*256; \
            int dr_ = f_ >> 3, u_ = f_ & 7; \
            glds16(vg0 + (size_t)dr_*SEQ + (kt)*64 + ((u_ ^ (dr_&7))*8), \
                   (unsigned short*)Vs[bb] + f_*8); \
        } }

    STAGE_KV(0, 0);
    asm volatile("s_waitcnt vmcnt(0)" ::: "memory");
    __builtin_amdgcn_s_barrier();

    int cur = 0;
    for (int kt=0; kt<SEQ/64; ++kt){
        // prefetch next tile under this tile's compute
        if (kt < SEQ/64 - 1) STAGE_KV(cur^1, kt+1);

        // ---- S = Q K^T ----
        f32x4 s[4];
        #pragma unroll
        for (int ct=0;ct<4;++ct){ s[ct][0]=0.f; s[ct][1]=0.f; s[ct][2]=0.f; s[ct][3]=0.f; }
        #pragma unroll
        for (int ct=0; ct<4; ++ct){
            const int kr = ct*16 + ln;
            const unsigned short* kb = Ks[cur] + kr*128;
            const int sw = kr & 7;
            #pragma unroll
            for (int c=0;c<4;++c){
                bf16x8 kf = *(const bf16x8*)(kb + ((((c<<2)|lg) ^ sw)*8));
                s[ct] = __builtin_amdgcn_mfma_f32_16x16x32_bf16(qf[c], kf, s[ct], 0,0,0);
            }
        }

        // ---- online softmax in exp2 domain, defer-max (THR=8) ----
        float mx[4];
        #pragma unroll
        for (int r=0;r<4;++r){
            float m_ = fmaxf(fmaxf(s[0][r], s[1][r]), fmaxf(s[2][r], s[3][r]));
            m_ = fmaxf(m_, __shfl_xor(m_,1));
            m_ = fmaxf(m_, __shfl_xor(m_,2));
            m_ = fmaxf(m_, __shfl_xor(m_,4));
            m_ = fmaxf(m_, __shfl_xor(m_,8));
            mx[r] = m_;
        }
        bool grow = false;
        #pragma unroll
        for (int r=0;r<4;++r) grow = grow || (mx[r] > mrun[r] + 8.f);
        if (__any(grow)){
            float al[4];
            #pragma unroll
            for (int r=0;r<4;++r){
                const float mn = fmaxf(mrun[r], mx[r]);
                al[r] = __builtin_amdgcn_exp2f(mrun[r]-mn);
                mrun[r] = mn;
                lrun[r] *= al[r];
            }
            #pragma unroll
            for (int dt=0;dt<8;++dt){
                o[dt][0]*=al[0]; o[dt][1]*=al[1]; o[dt][2]*=al[2]; o[dt][3]*=al[3];
            }
        }
        float pv[4][4];
        #pragma unroll
        for (int r=0;r<4;++r){
            float sum = 0.f;
            #pragma unroll
            for (int ct=0;ct<4;++ct){
                float p = __builtin_amdgcn_exp2f(s[ct][r]-mrun[r]);
                pv[r][ct] = p; sum += p;
            }
            sum += __shfl_xor(sum,1);
            sum += __shfl_xor(sum,2);
            sum += __shfl_xor(sum,4);
            sum += __shfl_xor(sum,8);
            lrun[r] += sum;
        }

        // ---- write P (bf16, per-wave swizzled LDS; same-wave consumer) ----
        #pragma unroll
        for (int r=0;r<4;++r){
            const int m = lg*4 + r;
            unsigned short* pr = Pw + m*64;
            const int sw = m & 7;
            #pragma unroll
            for (int ct=0;ct<4;++ct){
                int col = ct*16 + ln;
                pr[(((col>>3) ^ sw)*8) + (col&7)] = f2bf(pv[r][ct]);
            }
        }

        // ---- O += P V (V from LDS) ----
        #pragma unroll
        for (int kc=0;kc<2;++kc){
            bf16x8 pf = *(const bf16x8*)(Pw + ln*64 + ((((kc<<2)|lg) ^ lnsw)*8));
            #pragma unroll
            for (int dt=0;dt<8;++dt){
                const int vr = dt*16 + ln;
                bf16x8 vf = *(const bf16x8*)(Vs[cur] + vr*64 + ((((kc<<2)|lg) ^ lnsw)*8));
                o[dt] = __builtin_amdgcn_mfma_f32_16x16x32_bf16(pf, vf, o[dt], 0,0,0);
            }
        }

        if (kt < SEQ/64 - 1){
            asm volatile("s_waitcnt vmcnt(0)" ::: "memory");
            __builtin_amdgcn_s_barrier();
            cur ^= 1;
        }
    }
    #undef STAGE_KV

    const int b_ = bh >> 3, h_ = bh & 7;
    #pragma unroll
    for (int r=0;r<4;++r){
        const float inv = 1.0f / lrun[r];
        const int n_ = q0 + w*16 + lg*4 + r;
        float* op = out + ((size_t)(b_*SEQ) + n_)*1024 + h_*128 + ln;
        #pragma unroll
        for (int dt=0;dt<8;++dt)
            op[dt*16] = o[dt][r] * inv;
    }
}

extern "C" void kernel_launch(void* const* d_in, const int* in_sizes, int n_in,
                              void* d_out, int out_size, void* d_ws, size_t ws_size,
                              hipStream_t stream) {
    const float* x    = (const float*)d_in[0];
    const float* a    = (const float*)d_in[1];
    const float* Wx   = (const float*)d_in[2];
    const float* Wa   = (const float*)d_in[3];
    const float* g_qx = (const float*)d_in[4];
    const float* b_qx = (const float*)d_in[5];
    const float* g_kx = (const float*)d_in[6];
    const float* b_kx = (const float*)d_in[7];
    const float* g_qa = (const float*)d_in[8];
    const float* b_qa = (const float*)d_in[9];
    const float* g_ka = (const float*)d_in[10];
    const float* b_ka = (const float*)d_in[11];
    float* out = (float*)d_out;

    const size_t E = (size_t)BB*NH*SEQ*DH;        // 4,194,304 elements
    float* wsq = (float*)d_ws;                    // 16MB
    float* wsk = wsq + E;                         // 16MB
    unsigned short* Vt = (unsigned short*)(wsk + E);  // 8MB
    unsigned short* region = Vt + E;              // dual-use
    unsigned short* Ahi = region;                 // 8MB (gemm phase)
    unsigned short* Alo = region + E;             // 8MB
    unsigned short* Qb  = region;                 // 8MB (attn phase)
    unsigned short* Kb  = region + E;             // 8MB
    unsigned short* Bhi = region + 2*E;           // 3MB
    unsigned short* Blo = Bhi + (size_t)2*64*1536*8;  // 3MB
    float2* tab = (float2*)Bhi;                   // 512KB, reuses dead Bhi after GEMM

    prep_a<<<dim3(16, 64, 2), 256, 0, stream>>>(x, a, Ahi, Alo);
    prep_b<<<dim3(6, 64, 2), 256, 0, stream>>>(Wx, Wa, Bhi, Blo);
    qkv_mfma<<<dim3(32, 12, 2), 256, 0, stream>>>(Ahi, Alo, Bhi, Blo, wsq, wsk, Vt);
    rope_tab<<<dim3(256), 256, 0, stream>>>(tab);
    ln_rope<<<dim3(MROWS, 4), 512, 0, stream>>>(wsq, wsk, Qb, Kb, tab,
        g_qx, b_qx, g_kx, b_kx, g_qa, b_qa, g_ka, b_ka);
    attn_mfma<<<dim3(SEQ/64, BB*NH), 256, 0, stream>>>(Qb, Kb, Vt, out);
}

// Round 6
// 116.017 us; speedup vs baseline: 1.2558x; 1.0856x over previous
//
#include <hip/hip_runtime.h>
#include <math.h>

typedef __attribute__((ext_vector_type(8))) short bf16x8;
typedef __attribute__((ext_vector_type(4))) short bf16x4;
typedef __attribute__((ext_vector_type(4))) float f32x4;

#define BB    4
#define SEQ   1024
#define DIMV  512
#define TD    1536
#define NH    8
#define DH    128
#define MROWS (BB*SEQ)

__device__ inline unsigned short f2bf(float x){
    union { float f; unsigned u; } v; v.f = x;
    unsigned r = v.u + 0x7FFF + ((v.u >> 16) & 1);   // RNE
    return (unsigned short)(r >> 16);
}
__device__ inline float bf2f(unsigned short h){
    union { unsigned u; float f; } v; v.u = ((unsigned)h) << 16; return v.f;
}

__device__ inline void glds16(const void* g, void* l){
    __builtin_amdgcn_global_load_lds(
        (const __attribute__((address_space(1))) unsigned int*)g,
        (__attribute__((address_space(3))) unsigned int*)l,
        16, 0, 0);
}

// ---------------- Prep A: split x|a into hi/lo bf16, K-granule-major ----------------
__global__ __launch_bounds__(256) void prep_a(
    const float* __restrict__ X, const float* __restrict__ A,
    unsigned short* __restrict__ Ahi, unsigned short* __restrict__ Alo)
{
    const int m   = blockIdx.x*256 + threadIdx.x;
    const int pg  = blockIdx.y;         // p*4+g  (0..63)
    const int mat = blockIdx.z;
    const float* In = mat ? A : X;
    const float* src = In + (size_t)m*DIMV + pg*8;
    float4 v0 = *(const float4*)src;
    float4 v1 = *(const float4*)(src+4);
    float v[8] = {v0.x,v0.y,v0.z,v0.w,v1.x,v1.y,v1.z,v1.w};
    bf16x8 h, l;
    #pragma unroll
    for (int j=0;j<8;++j){
        unsigned short hb = f2bf(v[j]);
        h[j] = (short)hb;
        l[j] = (short)f2bf(v[j] - bf2f(hb));
    }
    const size_t o = ((size_t)(mat*64 + pg)*4096 + m)*8;
    *(bf16x8*)(Ahi+o) = h;
    *(bf16x8*)(Alo+o) = l;
}

// ---------------- Prep B: transpose+split W into hi/lo bf16, K-granule-major ----------
__global__ __launch_bounds__(256) void prep_b(
    const float* __restrict__ Wx, const float* __restrict__ Wa,
    unsigned short* __restrict__ Bhi, unsigned short* __restrict__ Blo)
{
    const int n   = blockIdx.x*256 + threadIdx.x;
    const int pg  = blockIdx.y;
    const int mat = blockIdx.z;
    const float* W = mat ? Wa : Wx;
    bf16x8 h, l;
    #pragma unroll
    for (int j=0;j<8;++j){
        float v = W[(size_t)(pg*8 + j)*TD + n];
        unsigned short hb = f2bf(v);
        h[j] = (short)hb;
        l[j] = (short)f2bf(v - bf2f(hb));
    }
    const size_t o = ((size_t)(mat*64 + pg)*1536 + n)*8;
    *(bf16x8*)(Bhi+o) = h;
    *(bf16x8*)(Blo+o) = l;
}

// ---------------- Kernel 1: QKV GEMM via bf16 MFMA, hi/lo 3-pass ----------------
__global__ __launch_bounds__(256,3) void qkv_mfma(
    const unsigned short* __restrict__ Ahi, const unsigned short* __restrict__ Alo,
    const unsigned short* __restrict__ Bhi, const unsigned short* __restrict__ Blo,
    float* __restrict__ wsq, float* __restrict__ wsk,
    unsigned short* __restrict__ Vt)
{
    __shared__ __align__(16) unsigned short sAh[4096];
    __shared__ __align__(16) unsigned short sAl[4096];
    __shared__ __align__(16) unsigned short sBh[4096];
    __shared__ __align__(16) unsigned short sBl[4096];

    const int mat = blockIdx.z;
    const int bm  = blockIdx.x * 128;
    const int bn  = blockIdx.y * 128;
    const int tid = threadIdx.x;
    const int w   = tid >> 6, l = tid & 63;
    const int wr  = w >> 1,  wc = w & 1;
    const int lg  = l >> 4,  ln = l & 15;

    f32x4 acc[4][4];
    #pragma unroll
    for (int i=0;i<4;++i)
        #pragma unroll
        for (int j=0;j<4;++j){ acc[i][j][0]=0.f; acc[i][j][1]=0.f; acc[i][j][2]=0.f; acc[i][j][3]=0.f; }

    const int g0 = tid >> 7, r0 = tid & 127;
    const size_t ASTEP = (size_t)4*4096*8;
    const size_t BSTEP = (size_t)4*1536*8;
    const unsigned short* a0h = Ahi + ((size_t)(mat*64 + g0)*4096 + bm + r0)*8;
    const unsigned short* a0l = Alo + ((size_t)(mat*64 + g0)*4096 + bm + r0)*8;
    const unsigned short* a1h = a0h + (size_t)2*4096*8;
    const unsigned short* a1l = a0l + (size_t)2*4096*8;
    const unsigned short* b0h = Bhi + ((size_t)(mat*64 + g0)*1536 + bn + r0)*8;
    const unsigned short* b0l = Blo + ((size_t)(mat*64 + g0)*1536 + bn + r0)*8;
    const unsigned short* b1h = b0h + (size_t)2*1536*8;
    const unsigned short* b1l = b0l + (size_t)2*1536*8;

    const int d0 = w*512, d1 = 2048 + w*512;

    for (int p=0; p<16; ++p){
        glds16(a0h, sAh + d0);  glds16(a1h, sAh + d1);
        glds16(a0l, sAl + d0);  glds16(a1l, sAl + d1);
        glds16(b0h, sBh + d0);  glds16(b1h, sBh + d1);
        glds16(b0l, sBl + d0);  glds16(b1l, sBl + d1);
        a0h += ASTEP; a1h += ASTEP; a0l += ASTEP; a1l += ASTEP;
        b0h += BSTEP; b1h += BSTEP; b0l += BSTEP; b1l += BSTEP;
        __syncthreads();

        bf16x8 ah[4], al[4], bh[4], bl[4];
        #pragma unroll
        for (int mi=0; mi<4; ++mi){
            const int off = (lg*128 + wr*64 + mi*16 + ln)*8;
            ah[mi] = *(const bf16x8*)(sAh + off);
            al[mi] = *(const bf16x8*)(sAl + off);
        }
        #pragma unroll
        for (int ni=0; ni<4; ++ni){
            const int off = (lg*128 + wc*64 + ni*16 + ln)*8;
            bh[ni] = *(const bf16x8*)(sBh + off);
            bl[ni] = *(const bf16x8*)(sBl + off);
        }
        #pragma unroll
        for (int mi=0; mi<4; ++mi)
            #pragma unroll
            for (int ni=0; ni<4; ++ni){
                acc[mi][ni] = __builtin_amdgcn_mfma_f32_16x16x32_bf16(ah[mi], bh[ni], acc[mi][ni], 0,0,0);
                acc[mi][ni] = __builtin_amdgcn_mfma_f32_16x16x32_bf16(ah[mi], bl[ni], acc[mi][ni], 0,0,0);
                acc[mi][ni] = __builtin_amdgcn_mfma_f32_16x16x32_bf16(al[mi], bh[ni], acc[mi][ni], 0,0,0);
            }
        __syncthreads();
    }

    const int b_ = bm >> 10;
    const int n0base = (bm & 1023) + wr*64;
    const int colB = bn + wc*64;
    if (colB < 1024){
        float* base = (colB < 512) ? wsq : wsk;
        #pragma unroll
        for (int ni=0; ni<4; ++ni){
            const int col = colB + ni*16 + ln;
            const int h = mat*4 + ((col >> 7) & 3);
            const int d = col & 127;
            #pragma unroll
            for (int mi=0; mi<4; ++mi){
                const int n0 = n0base + mi*16 + lg*4;
                float* dst = base + ((size_t)(b_*NH + h)*SEQ + n0)*DH + d;
                #pragma unroll
                for (int r=0;r<4;++r) dst[r*DH] = acc[mi][ni][r];
            }
        }
    } else {
        #pragma unroll
        for (int ni=0; ni<4; ++ni){
            const int col = colB + ni*16 + ln;
            const int h = mat*4 + ((col >> 7) & 3);
            const int d = col & 127;
            #pragma unroll
            for (int mi=0; mi<4; ++mi){
                const int n0 = n0base + mi*16 + lg*4;
                unsigned short* dst = Vt + ((size_t)(b_*NH + h)*DH + d)*SEQ + n0;
                bf16x4 pk;
                #pragma unroll
                for (int r=0;r<4;++r) pk[r] = (short)f2bf(acc[mi][ni][r]);
                *(bf16x4*)dst = pk;
            }
        }
    }
}

// ---------------- RoPE cos/sin table ----------------
__global__ __launch_bounds__(256) void rope_tab(float2* __restrict__ tab)
{
    const int i = blockIdx.x*256 + threadIdx.x;   // 65536
    const int n = i >> 6, dd = i & 63;
    const float inv = expf((float)dd * (1.f/64.f) * -9.210340371976184f);
    const float ang = (float)n * inv;
    float sn, cs;
    sincosf(ang, &sn, &cs);
    tab[i] = make_float2(cs, sn);
}

// ---------------- Kernel 2: LayerNorm + RoPE -> bf16 ----------------
__global__ __launch_bounds__(512) void ln_rope(
    const float* __restrict__ wsq, const float* __restrict__ wsk,
    unsigned short* __restrict__ Qb, unsigned short* __restrict__ Kb,
    const float2* __restrict__ tab,
    const float* __restrict__ g_qx, const float* __restrict__ b_qx,
    const float* __restrict__ g_kx, const float* __restrict__ b_kx,
    const float* __restrict__ g_qa, const float* __restrict__ b_qa,
    const float* __restrict__ g_ka, const float* __restrict__ b_ka)
{
    __shared__ float red[16];
    __shared__ float vn[512];
    const int r = blockIdx.x;
    const int which = blockIdx.y;
    const int b_ = r >> 10;
    const int n_ = r & 1023;
    const float* buf = (which & 1) ? wsk : wsq;
    unsigned short* ob = (which & 1) ? Kb : Qb;
    const int h0 = (which >> 1) ? 4 : 0;
    const float* g; const float* bb;
    if (which==0){ g=g_qx; bb=b_qx; }
    else if (which==1){ g=g_kx; bb=b_kx; }
    else if (which==2){ g=g_qa; bb=b_qa; }
    else { g=g_ka; bb=b_ka; }

    const int t = threadIdx.x;
    const int h = h0 + (t >> 7);
    const int d = t & 127;
    const size_t idx = ((size_t)(b_*NH + h)*SEQ + n_)*DH + d;
    float v = buf[idx];
    float s1 = v, s2 = v*v;
    #pragma unroll
    for (int o=32;o>=1;o>>=1){
        s1 += __shfl_down(s1,o);
        s2 += __shfl_down(s2,o);
    }
    const int lane = t & 63, wv = t >> 6;
    if (lane==0){ red[wv]=s1; red[8+wv]=s2; }
    __syncthreads();
    float sum=0.f, sq=0.f;
    #pragma unroll
    for (int w=0;w<8;++w){ sum+=red[w]; sq+=red[8+w]; }
    const float mu = sum * (1.f/512.f);
    const float var = sq * (1.f/512.f) - mu*mu;
    const float rs = rsqrtf(var + 1e-5f);
    const float xn = (v - mu)*rs*g[t] + bb[t];
    vn[t] = xn;
    __syncthreads();
    const float partner = vn[t ^ 64];
    const float2 cssn = tab[(n_ << 6) + (d & 63)];
    const float rot = (d < 64) ? -partner : partner;
    float val = xn*cssn.x + rot*cssn.y;
    // fold 1/sqrt(128) * log2(e) into Q (softmax runs in exp2 domain)
    if (!(which & 1)) val *= 0.08838834764831845f * 1.4426950408889634f;
    ob[idx] = f2bf(val);
}

// ---------------- Kernel 3: MFMA flash attention (bf16), swapped-QK^T ----------------
// 4 waves x 16 q-rows. S^T = mfma(K,Q): each lane owns q-row ln -> in-lane softmax.
// P packed via v_cvt_pk_bf16_f32, 4x ds_write_b64 (swizzled), read back as A-frag b128.
// K/V staged via global_load_lds (pre-swizzled source), double-buffered, 1 barrier/iter.
__global__ __launch_bounds__(256,2) void attn_mfma(
    const unsigned short* __restrict__ Qb, const unsigned short* __restrict__ Kb,
    const unsigned short* __restrict__ Vt, float* __restrict__ out)
{
    __shared__ __align__(16) unsigned short Ks[2][64*128];  // 2 x 16KB
    __shared__ __align__(16) unsigned short Vs[2][128*64];  // 2 x 16KB (V^T)
    __shared__ __align__(16) unsigned short Ps[4*16*64];    // 8KB (2KB per wave)

    // XCD-aware remap: blocks sharing (b,h) land on one XCD (K/V L2 locality)
    const int nblk = blockIdx.x;
    const int jj  = nblk >> 3;
    const int bh  = (nblk & 7)*4 + (jj >> 4);
    const int q0  = (jj & 15) * 64;

    const int tid = threadIdx.x;
    const int w  = tid >> 6;
    const int l  = tid & 63;
    const int lg = l >> 4;
    const int ln = l & 15;
    const size_t hoff = (size_t)bh * SEQ * DH;

    bf16x8 qf[4];
    {
        const unsigned short* qp = Qb + hoff + (size_t)(q0 + w*16 + ln)*DH + lg*8;
        #pragma unroll
        for (int c=0;c<4;++c) qf[c] = *(const bf16x8*)(qp + c*32);
    }

    f32x4 o[8];
    #pragma unroll
    for (int dt=0;dt<8;++dt){ o[dt][0]=0.f; o[dt][1]=0.f; o[dt][2]=0.f; o[dt][3]=0.f; }
    float mrun = -INFINITY, lrun = 0.f;   // per-lane state for q-row = ln

    const unsigned short* kg0 = Kb + hoff;
    const unsigned short* vg0 = Vt + hoff;
    char* Pw = (char*)(Ps + w*1024);
    const int psw = (ln & 7) << 4;

    #define STAGE_KV(bb, kt) { \
        const unsigned short* kg_ = kg0 + (size_t)(kt)*64*128; \
        _Pragma("unroll") \
        for (int i_=0;i_<4;++i_){ \
            int f_ = tid + i_*256; \
            int r_ = f_ >> 4, s_ = f_ & 15; \
            glds16(kg_ + r_*128 + ((s_ ^ (r_&7))*8), (unsigned short*)Ks[bb] + f_*8); \
        } \
        _Pragma("unroll") \
        for (int i_=0;i_<4;++i_){ \
            int f_ = tid + i_*256; \
            int dr_ = f_ >> 3, u_ = f_ & 7; \
            glds16(vg0 + (size_t)dr_*SEQ + (kt)*64 + ((u_ ^ (dr_&7))*8), \
                   (unsigned short*)Vs[bb] + f_*8); \
        } }

    STAGE_KV(0, 0);
    asm volatile("s_waitcnt vmcnt(0)" ::: "memory");
    __builtin_amdgcn_s_barrier();

    int cur = 0;
    for (int kt=0; kt<SEQ/64; ++kt){
        if (kt < SEQ/64 - 1) STAGE_KV(cur^1, kt+1);

        // ---- S^T = K Q^T : lane (ln,lg) gets S[key=ct*16+lg*4+r][q=ln] ----
        f32x4 s[4];
        #pragma unroll
        for (int ct=0;ct<4;++ct){ s[ct][0]=0.f; s[ct][1]=0.f; s[ct][2]=0.f; s[ct][3]=0.f; }
        #pragma unroll
        for (int ct=0; ct<4; ++ct){
            const int kr = ct*16 + ln;
            const unsigned short* kb = Ks[cur] + kr*128;
            const int sw = kr & 7;
            #pragma unroll
            for (int c=0;c<4;++c){
                bf16x8 kf = *(const bf16x8*)(kb + ((((c<<2)|lg) ^ sw)*8));
                s[ct] = __builtin_amdgcn_mfma_f32_16x16x32_bf16(kf, qf[c], s[ct], 0,0,0);
            }
        }

        // ---- in-lane softmax (exp2 domain, defer-max THR=8) ----
        float m01 = fmaxf(fmaxf(s[0][0],s[0][1]), fmaxf(s[0][2],s[0][3]));
        float m23 = fmaxf(fmaxf(s[1][0],s[1][1]), fmaxf(s[1][2],s[1][3]));
        float m45 = fmaxf(fmaxf(s[2][0],s[2][1]), fmaxf(s[2][2],s[2][3]));
        float m67 = fmaxf(fmaxf(s[3][0],s[3][1]), fmaxf(s[3][2],s[3][3]));
        float mloc = fmaxf(fmaxf(m01,m23), fmaxf(m45,m67));
        float mx = fmaxf(mloc, __shfl_xor(mloc,16));
        mx = fmaxf(mx, __shfl_xor(mx,32));
        if (__any(mx > mrun + 8.f)){
            const float mn = fmaxf(mrun, mx);
            const float al = __builtin_amdgcn_exp2f(mrun - mn);
            mrun = mn; lrun *= al;
            float alr[4];
            #pragma unroll
            for (int r=0;r<4;++r) alr[r] = __shfl(al, lg*4 + r);
            #pragma unroll
            for (int dt=0;dt<8;++dt){
                o[dt][0]*=alr[0]; o[dt][1]*=alr[1]; o[dt][2]*=alr[2]; o[dt][3]*=alr[3];
            }
        }
        float p[4][4];
        float su = 0.f;
        #pragma unroll
        for (int ct=0;ct<4;++ct){
            #pragma unroll
            for (int r=0;r<4;++r){
                p[ct][r] = __builtin_amdgcn_exp2f(s[ct][r]-mrun);
            }
            su += (p[ct][0]+p[ct][1]) + (p[ct][2]+p[ct][3]);
        }
        su += __shfl_xor(su,16);
        su += __shfl_xor(su,32);
        lrun += su;

        // ---- pack P (cvt_pk pairs) + 4x ds_write_b64, XOR-swizzled ----
        #pragma unroll
        for (int ct=0;ct<4;++ct){
            unsigned dw0, dw1;
            asm("v_cvt_pk_bf16_f32 %0, %1, %2" : "=v"(dw0) : "v"(p[ct][0]), "v"(p[ct][1]));
            asm("v_cvt_pk_bf16_f32 %0, %1, %2" : "=v"(dw1) : "v"(p[ct][2]), "v"(p[ct][3]));
            const int byte = ln*128 + ((ct*32 + lg*8) ^ psw);
            *(uint2*)(Pw + byte) = make_uint2(dw0, dw1);
        }

        // ---- O += P V : A-frag P (q=ln rows), B-frag V^T from LDS ----
        #pragma unroll
        for (int kc=0;kc<2;++kc){
            const int pb = ln*128 + ((kc*64 + lg*16) ^ psw);
            bf16x8 pf = *(const bf16x8*)(Pw + pb);
            #pragma unroll
            for (int dt=0;dt<8;++dt){
                const int vr = dt*16 + ln;
                bf16x8 vf = *(const bf16x8*)(Vs[cur] + vr*64 + ((((kc<<2)|lg) ^ (ln&7))*8));
                o[dt] = __builtin_amdgcn_mfma_f32_16x16x32_bf16(pf, vf, o[dt], 0,0,0);
            }
        }

        if (kt < SEQ/64 - 1){
            asm volatile("s_waitcnt vmcnt(0)" ::: "memory");
            __builtin_amdgcn_s_barrier();
            cur ^= 1;
        }
    }
    #undef STAGE_KV

    // ---- epilogue: broadcast 1/l to row-form, store ----
    const float linv = 1.0f / lrun;
    float lr[4];
    #pragma unroll
    for (int r=0;r<4;++r) lr[r] = __shfl(linv, lg*4 + r);

    const int b_ = bh >> 3, h_ = bh & 7;
    #pragma unroll
    for (int r=0;r<4;++r){
        const int n_ = q0 + w*16 + lg*4 + r;
        float* op = out + ((size_t)(b_*SEQ) + n_)*1024 + h_*128 + ln;
        #pragma unroll
        for (int dt=0;dt<8;++dt)
            op[dt*16] = o[dt][r] * lr[r];
    }
}

extern "C" void kernel_launch(void* const* d_in, const int* in_sizes, int n_in,
                              void* d_out, int out_size, void* d_ws, size_t ws_size,
                              hipStream_t stream) {
    const float* x    = (const float*)d_in[0];
    const float* a    = (const float*)d_in[1];
    const float* Wx   = (const float*)d_in[2];
    const float* Wa   = (const float*)d_in[3];
    const float* g_qx = (const float*)d_in[4];
    const float* b_qx = (const float*)d_in[5];
    const float* g_kx = (const float*)d_in[6];
    const float* b_kx = (const float*)d_in[7];
    const float* g_qa = (const float*)d_in[8];
    const float* b_qa = (const float*)d_in[9];
    const float* g_ka = (const float*)d_in[10];
    const float* b_ka = (const float*)d_in[11];
    float* out = (float*)d_out;

    const size_t E = (size_t)BB*NH*SEQ*DH;        // 4,194,304 elements
    float* wsq = (float*)d_ws;                    // 16MB
    float* wsk = wsq + E;                         // 16MB
    unsigned short* Vt = (unsigned short*)(wsk + E);  // 8MB
    unsigned short* region = Vt + E;              // dual-use
    unsigned short* Ahi = region;                 // 8MB (gemm phase)
    unsigned short* Alo = region + E;             // 8MB
    unsigned short* Qb  = region;                 // 8MB (attn phase)
    unsigned short* Kb  = region + E;             // 8MB
    unsigned short* Bhi = region + 2*E;           // 3MB
    unsigned short* Blo = Bhi + (size_t)2*64*1536*8;  // 3MB
    float2* tab = (float2*)Bhi;                   // 512KB, reuses dead Bhi after GEMM

    prep_a<<<dim3(16, 64, 2), 256, 0, stream>>>(x, a, Ahi, Alo);
    prep_b<<<dim3(6, 64, 2), 256, 0, stream>>>(Wx, Wa, Bhi, Blo);
    qkv_mfma<<<dim3(32, 12, 2), 256, 0, stream>>>(Ahi, Alo, Bhi, Blo, wsq, wsk, Vt);
    rope_tab<<<dim3(256), 256, 0, stream>>>(tab);
    ln_rope<<<dim3(MROWS, 4), 512, 0, stream>>>(wsq, wsk, Qb, Kb, tab,
        g_qx, b_qx, g_kx, b_kx, g_qa, b_qa, g_ka, b_ka);
    attn_mfma<<<dim3(512), 256, 0, stream>>>(Qb, Kb, Vt, out);
}

// Round 7
// 103.767 us; speedup vs baseline: 1.4040x; 1.1181x over previous
//
#include <hip/hip_runtime.h>
#include <math.h>

typedef __attribute__((ext_vector_type(8))) short bf16x8;
typedef __attribute__((ext_vector_type(4))) short bf16x4;
typedef __attribute__((ext_vector_type(4))) float f32x4;

#define BB    4
#define SEQ   1024
#define DIMV  512
#define TD    1536
#define NH    8
#define DH    128
#define MROWS (BB*SEQ)

__device__ inline unsigned short f2bf(float x){
    union { float f; unsigned u; } v; v.f = x;
    unsigned r = v.u + 0x7FFF + ((v.u >> 16) & 1);   // RNE
    return (unsigned short)(r >> 16);
}
__device__ inline float bf2f(unsigned short h){
    union { unsigned u; float f; } v; v.u = ((unsigned)h) << 16; return v.f;
}

__device__ inline void glds16(const void* g, void* l){
    __builtin_amdgcn_global_load_lds(
        (const __attribute__((address_space(1))) unsigned int*)g,
        (__attribute__((address_space(3))) unsigned int*)l,
        16, 0, 0);
}

// ---------------- Prep A: x|a -> bf16, K-granule-major ----------------
// Layout: Ab[(mat*64 + p*4+g)*4096 + m][8] holds In[m][p*32+g*8 .. +7]
__global__ __launch_bounds__(256) void prep_a(
    const float* __restrict__ X, const float* __restrict__ A,
    unsigned short* __restrict__ Ab)
{
    const int m   = blockIdx.x*256 + threadIdx.x;
    const int pg  = blockIdx.y;         // p*4+g  (0..63)
    const int mat = blockIdx.z;
    const float* In = mat ? A : X;
    const float* src = In + (size_t)m*DIMV + pg*8;
    float4 v0 = *(const float4*)src;
    float4 v1 = *(const float4*)(src+4);
    float v[8] = {v0.x,v0.y,v0.z,v0.w,v1.x,v1.y,v1.z,v1.w};
    bf16x8 h;
    #pragma unroll
    for (int j=0;j<8;++j) h[j] = (short)f2bf(v[j]);
    const size_t o = ((size_t)(mat*64 + pg)*4096 + m)*8;
    *(bf16x8*)(Ab+o) = h;
}

// ---------------- Prep B: transpose+split W into hi/lo bf16, K-granule-major ----------
__global__ __launch_bounds__(256) void prep_b(
    const float* __restrict__ Wx, const float* __restrict__ Wa,
    unsigned short* __restrict__ Bhi, unsigned short* __restrict__ Blo)
{
    const int n   = blockIdx.x*256 + threadIdx.x;
    const int pg  = blockIdx.y;
    const int mat = blockIdx.z;
    const float* W = mat ? Wa : Wx;
    bf16x8 h, l;
    #pragma unroll
    for (int j=0;j<8;++j){
        float v = W[(size_t)(pg*8 + j)*TD + n];
        unsigned short hb = f2bf(v);
        h[j] = (short)hb;
        l[j] = (short)f2bf(v - bf2f(hb));
    }
    const size_t o = ((size_t)(mat*64 + pg)*1536 + n)*8;
    *(bf16x8*)(Bhi+o) = h;
    *(bf16x8*)(Blo+o) = l;
}

// ---------------- Kernel 1: QKV GEMM via bf16 MFMA, 2-pass (A bf16, W hi/lo) --------
// 128x128 tile, BK=32, 4 waves (2x2 quadrants of 64x64). LDS 24KB.
__global__ __launch_bounds__(256,3) void qkv_mfma(
    const unsigned short* __restrict__ Ab,
    const unsigned short* __restrict__ Bhi, const unsigned short* __restrict__ Blo,
    float* __restrict__ wsq, float* __restrict__ wsk,
    unsigned short* __restrict__ Vt)
{
    __shared__ __align__(16) unsigned short sA [4096];
    __shared__ __align__(16) unsigned short sBh[4096];
    __shared__ __align__(16) unsigned short sBl[4096];

    const int mat = blockIdx.z;
    const int bm  = blockIdx.x * 128;
    const int bn  = blockIdx.y * 128;
    const int tid = threadIdx.x;
    const int w   = tid >> 6, l = tid & 63;
    const int wr  = w >> 1,  wc = w & 1;
    const int lg  = l >> 4,  ln = l & 15;

    f32x4 acc[4][4];
    #pragma unroll
    for (int i=0;i<4;++i)
        #pragma unroll
        for (int j=0;j<4;++j){ acc[i][j][0]=0.f; acc[i][j][1]=0.f; acc[i][j][2]=0.f; acc[i][j][3]=0.f; }

    const int g0 = tid >> 7, r0 = tid & 127;
    const size_t ASTEP = (size_t)4*4096*8;
    const size_t BSTEP = (size_t)4*1536*8;
    const unsigned short* a0  = Ab  + ((size_t)(mat*64 + g0)*4096 + bm + r0)*8;
    const unsigned short* a1  = a0 + (size_t)2*4096*8;
    const unsigned short* b0h = Bhi + ((size_t)(mat*64 + g0)*1536 + bn + r0)*8;
    const unsigned short* b0l = Blo + ((size_t)(mat*64 + g0)*1536 + bn + r0)*8;
    const unsigned short* b1h = b0h + (size_t)2*1536*8;
    const unsigned short* b1l = b0l + (size_t)2*1536*8;

    const int d0 = w*512, d1 = 2048 + w*512;

    for (int p=0; p<16; ++p){
        glds16(a0,  sA  + d0);  glds16(a1,  sA  + d1);
        glds16(b0h, sBh + d0);  glds16(b1h, sBh + d1);
        glds16(b0l, sBl + d0);  glds16(b1l, sBl + d1);
        a0 += ASTEP; a1 += ASTEP;
        b0h += BSTEP; b1h += BSTEP; b0l += BSTEP; b1l += BSTEP;
        __syncthreads();

        bf16x8 av[4], bh[4], bl[4];
        #pragma unroll
        for (int mi=0; mi<4; ++mi){
            const int off = (lg*128 + wr*64 + mi*16 + ln)*8;
            av[mi] = *(const bf16x8*)(sA + off);
        }
        #pragma unroll
        for (int ni=0; ni<4; ++ni){
            const int off = (lg*128 + wc*64 + ni*16 + ln)*8;
            bh[ni] = *(const bf16x8*)(sBh + off);
            bl[ni] = *(const bf16x8*)(sBl + off);
        }
        #pragma unroll
        for (int mi=0; mi<4; ++mi)
            #pragma unroll
            for (int ni=0; ni<4; ++ni){
                acc[mi][ni] = __builtin_amdgcn_mfma_f32_16x16x32_bf16(av[mi], bh[ni], acc[mi][ni], 0,0,0);
                acc[mi][ni] = __builtin_amdgcn_mfma_f32_16x16x32_bf16(av[mi], bl[ni], acc[mi][ni], 0,0,0);
            }
        __syncthreads();
    }

    const int b_ = bm >> 10;
    const int n0base = (bm & 1023) + wr*64;
    const int colB = bn + wc*64;
    if (colB < 1024){
        float* base = (colB < 512) ? wsq : wsk;
        #pragma unroll
        for (int ni=0; ni<4; ++ni){
            const int col = colB + ni*16 + ln;
            const int h = mat*4 + ((col >> 7) & 3);
            const int d = col & 127;
            #pragma unroll
            for (int mi=0; mi<4; ++mi){
                const int n0 = n0base + mi*16 + lg*4;
                float* dst = base + ((size_t)(b_*NH + h)*SEQ + n0)*DH + d;
                #pragma unroll
                for (int r=0;r<4;++r) dst[r*DH] = acc[mi][ni][r];
            }
        }
    } else {
        #pragma unroll
        for (int ni=0; ni<4; ++ni){
            const int col = colB + ni*16 + ln;
            const int h = mat*4 + ((col >> 7) & 3);
            const int d = col & 127;
            #pragma unroll
            for (int mi=0; mi<4; ++mi){
                const int n0 = n0base + mi*16 + lg*4;
                unsigned short* dst = Vt + ((size_t)(b_*NH + h)*DH + d)*SEQ + n0;
                bf16x4 pk;
                #pragma unroll
                for (int r=0;r<4;++r) pk[r] = (short)f2bf(acc[mi][ni][r]);
                *(bf16x4*)dst = pk;
            }
        }
    }
}

// ---------------- RoPE cos/sin table ----------------
__global__ __launch_bounds__(256) void rope_tab(float2* __restrict__ tab)
{
    const int i = blockIdx.x*256 + threadIdx.x;   // 65536
    const int n = i >> 6, dd = i & 63;
    const float inv = expf((float)dd * (1.f/64.f) * -9.210340371976184f);
    const float ang = (float)n * inv;
    float sn, cs;
    sincosf(ang, &sn, &cs);
    tab[i] = make_float2(cs, sn);
}

// ---------------- Kernel 2: LayerNorm + RoPE -> bf16 ----------------
__global__ __launch_bounds__(512) void ln_rope(
    const float* __restrict__ wsq, const float* __restrict__ wsk,
    unsigned short* __restrict__ Qb, unsigned short* __restrict__ Kb,
    const float2* __restrict__ tab,
    const float* __restrict__ g_qx, const float* __restrict__ b_qx,
    const float* __restrict__ g_kx, const float* __restrict__ b_kx,
    const float* __restrict__ g_qa, const float* __restrict__ b_qa,
    const float* __restrict__ g_ka, const float* __restrict__ b_ka)
{
    __shared__ float red[16];
    __shared__ float vn[512];
    const int r = blockIdx.x;
    const int which = blockIdx.y;
    const int b_ = r >> 10;
    const int n_ = r & 1023;
    const float* buf = (which & 1) ? wsk : wsq;
    unsigned short* ob = (which & 1) ? Kb : Qb;
    const int h0 = (which >> 1) ? 4 : 0;
    const float* g; const float* bb;
    if (which==0){ g=g_qx; bb=b_qx; }
    else if (which==1){ g=g_kx; bb=b_kx; }
    else if (which==2){ g=g_qa; bb=b_qa; }
    else { g=g_ka; bb=b_ka; }

    const int t = threadIdx.x;
    const int h = h0 + (t >> 7);
    const int d = t & 127;
    const size_t idx = ((size_t)(b_*NH + h)*SEQ + n_)*DH + d;
    float v = buf[idx];
    float s1 = v, s2 = v*v;
    #pragma unroll
    for (int o=32;o>=1;o>>=1){
        s1 += __shfl_down(s1,o);
        s2 += __shfl_down(s2,o);
    }
    const int lane = t & 63, wv = t >> 6;
    if (lane==0){ red[wv]=s1; red[8+wv]=s2; }
    __syncthreads();
    float sum=0.f, sq=0.f;
    #pragma unroll
    for (int w=0;w<8;++w){ sum+=red[w]; sq+=red[8+w]; }
    const float mu = sum * (1.f/512.f);
    const float var = sq * (1.f/512.f) - mu*mu;
    const float rs = rsqrtf(var + 1e-5f);
    const float xn = (v - mu)*rs*g[t] + bb[t];
    vn[t] = xn;
    __syncthreads();
    const float partner = vn[t ^ 64];
    const float2 cssn = tab[(n_ << 6) + (d & 63)];
    const float rot = (d < 64) ? -partner : partner;
    float val = xn*cssn.x + rot*cssn.y;
    // fold 1/sqrt(128) * log2(e) into Q (softmax runs in exp2 domain)
    if (!(which & 1)) val *= 0.08838834764831845f * 1.4426950408889634f;
    ob[idx] = f2bf(val);
}

// ---------------- Kernel 3: MFMA flash attention (bf16), swapped-QK^T ----------------
__global__ __launch_bounds__(256,2) void attn_mfma(
    const unsigned short* __restrict__ Qb, const unsigned short* __restrict__ Kb,
    const unsigned short* __restrict__ Vt, float* __restrict__ out)
{
    __shared__ __align__(16) unsigned short Ks[2][64*128];  // 2 x 16KB
    __shared__ __align__(16) unsigned short Vs[2][128*64];  // 2 x 16KB (V^T)
    __shared__ __align__(16) unsigned short Ps[4*16*64];    // 8KB (2KB per wave)

    // XCD-aware remap: blocks sharing (b,h) land on one XCD (K/V L2 locality)
    const int nblk = blockIdx.x;
    const int jj  = nblk >> 3;
    const int bh  = (nblk & 7)*4 + (jj >> 4);
    const int q0  = (jj & 15) * 64;

    const int tid = threadIdx.x;
    const int w  = tid >> 6;
    const int l  = tid & 63;
    const int lg = l >> 4;
    const int ln = l & 15;
    const size_t hoff = (size_t)bh * SEQ * DH;

    bf16x8 qf[4];
    {
        const unsigned short* qp = Qb + hoff + (size_t)(q0 + w*16 + ln)*DH + lg*8;
        #pragma unroll
        for (int c=0;c<4;++c) qf[c] = *(const bf16x8*)(qp + c*32);
    }

    f32x4 o[8];
    #pragma unroll
    for (int dt=0;dt<8;++dt){ o[dt][0]=0.f; o[dt][1]=0.f; o[dt][2]=0.f; o[dt][3]=0.f; }
    float mrun = -INFINITY, lrun = 0.f;   // per-lane state for q-row = ln

    const unsigned short* kg0 = Kb + hoff;
    const unsigned short* vg0 = Vt + hoff;
    char* Pw = (char*)(Ps + w*1024);
    const int psw = (ln & 7) << 4;

    #define STAGE_KV(bb, kt) { \
        const unsigned short* kg_ = kg0 + (size_t)(kt)*64*128; \
        _Pragma("unroll") \
        for (int i_=0;i_<4;++i_){ \
            int f_ = tid + i_*256; \
            int r_ = f_ >> 4, s_ = f_ & 15; \
            glds16(kg_ + r_*128 + ((s_ ^ (r_&7))*8), (unsigned short*)Ks[bb] + f_*8); \
        } \
        _Pragma("unroll") \
        for (int i_=0;i_<4;++i_){ \
            int f_ = tid + i_*256; \
            int dr_ = f_ >> 3, u_ = f_ & 7; \
            glds16(vg0 + (size_t)dr_*SEQ + (kt)*64 + ((u_ ^ (dr_&7))*8), \
                   (unsigned short*)Vs[bb] + f_*8); \
        } }

    STAGE_KV(0, 0);
    asm volatile("s_waitcnt vmcnt(0)" ::: "memory");
    __builtin_amdgcn_s_barrier();

    int cur = 0;
    for (int kt=0; kt<SEQ/64; ++kt){
        if (kt < SEQ/64 - 1) STAGE_KV(cur^1, kt+1);

        // ---- S^T = K Q^T : lane (ln,lg) gets S[key=ct*16+lg*4+r][q=ln] ----
        f32x4 s[4];
        #pragma unroll
        for (int ct=0;ct<4;++ct){ s[ct][0]=0.f; s[ct][1]=0.f; s[ct][2]=0.f; s[ct][3]=0.f; }
        #pragma unroll
        for (int ct=0; ct<4; ++ct){
            const int kr = ct*16 + ln;
            const unsigned short* kb = Ks[cur] + kr*128;
            const int sw = kr & 7;
            #pragma unroll
            for (int c=0;c<4;++c){
                bf16x8 kf = *(const bf16x8*)(kb + ((((c<<2)|lg) ^ sw)*8));
                s[ct] = __builtin_amdgcn_mfma_f32_16x16x32_bf16(kf, qf[c], s[ct], 0,0,0);
            }
        }

        // ---- in-lane softmax (exp2 domain, defer-max THR=8) ----
        float m01 = fmaxf(fmaxf(s[0][0],s[0][1]), fmaxf(s[0][2],s[0][3]));
        float m23 = fmaxf(fmaxf(s[1][0],s[1][1]), fmaxf(s[1][2],s[1][3]));
        float m45 = fmaxf(fmaxf(s[2][0],s[2][1]), fmaxf(s[2][2],s[2][3]));
        float m67 = fmaxf(fmaxf(s[3][0],s[3][1]), fmaxf(s[3][2],s[3][3]));
        float mloc = fmaxf(fmaxf(m01,m23), fmaxf(m45,m67));
        float mx = fmaxf(mloc, __shfl_xor(mloc,16));
        mx = fmaxf(mx, __shfl_xor(mx,32));
        if (__any(mx > mrun + 8.f)){
            const float mn = fmaxf(mrun, mx);
            const float al = __builtin_amdgcn_exp2f(mrun - mn);
            mrun = mn; lrun *= al;
            float alr[4];
            #pragma unroll
            for (int r=0;r<4;++r) alr[r] = __shfl(al, lg*4 + r);
            #pragma unroll
            for (int dt=0;dt<8;++dt){
                o[dt][0]*=alr[0]; o[dt][1]*=alr[1]; o[dt][2]*=alr[2]; o[dt][3]*=alr[3];
            }
        }
        float p[4][4];
        float su = 0.f;
        #pragma unroll
        for (int ct=0;ct<4;++ct){
            #pragma unroll
            for (int r=0;r<4;++r){
                p[ct][r] = __builtin_amdgcn_exp2f(s[ct][r]-mrun);
            }
            su += (p[ct][0]+p[ct][1]) + (p[ct][2]+p[ct][3]);
        }
        su += __shfl_xor(su,16);
        su += __shfl_xor(su,32);
        lrun += su;

        // ---- pack P (cvt_pk pairs) + 4x ds_write_b64, XOR-swizzled ----
        #pragma unroll
        for (int ct=0;ct<4;++ct){
            unsigned dw0, dw1;
            asm("v_cvt_pk_bf16_f32 %0, %1, %2" : "=v"(dw0) : "v"(p[ct][0]), "v"(p[ct][1]));
            asm("v_cvt_pk_bf16_f32 %0, %1, %2" : "=v"(dw1) : "v"(p[ct][2]), "v"(p[ct][3]));
            const int byte = ln*128 + ((ct*32 + lg*8) ^ psw);
            *(uint2*)(Pw + byte) = make_uint2(dw0, dw1);
        }

        // ---- O += P V : A-frag P (q=ln rows), B-frag V^T from LDS ----
        #pragma unroll
        for (int kc=0;kc<2;++kc){
            const int pb = ln*128 + ((kc*64 + lg*16) ^ psw);
            bf16x8 pf = *(const bf16x8*)(Pw + pb);
            #pragma unroll
            for (int dt=0;dt<8;++dt){
                const int vr = dt*16 + ln;
                bf16x8 vf = *(const bf16x8*)(Vs[cur] + vr*64 + ((((kc<<2)|lg) ^ (ln&7))*8));
                o[dt] = __builtin_amdgcn_mfma_f32_16x16x32_bf16(pf, vf, o[dt], 0,0,0);
            }
        }

        if (kt < SEQ/64 - 1){
            asm volatile("s_waitcnt vmcnt(0)" ::: "memory");
            __builtin_amdgcn_s_barrier();
            cur ^= 1;
        }
    }
    #undef STAGE_KV

    // ---- epilogue: broadcast 1/l to row-form, store ----
    const float linv = 1.0f / lrun;
    float lr[4];
    #pragma unroll
    for (int r=0;r<4;++r) lr[r] = __shfl(linv, lg*4 + r);

    const int b_ = bh >> 3, h_ = bh & 7;
    #pragma unroll
    for (int r=0;r<4;++r){
        const int n_ = q0 + w*16 + lg*4 + r;
        float* op = out + ((size_t)(b_*SEQ) + n_)*1024 + h_*128 + ln;
        #pragma unroll
        for (int dt=0;dt<8;++dt)
            op[dt*16] = o[dt][r] * lr[r];
    }
}

extern "C" void kernel_launch(void* const* d_in, const int* in_sizes, int n_in,
                              void* d_out, int out_size, void* d_ws, size_t ws_size,
                              hipStream_t stream) {
    const float* x    = (const float*)d_in[0];
    const float* a    = (const float*)d_in[1];
    const float* Wx   = (const float*)d_in[2];
    const float* Wa   = (const float*)d_in[3];
    const float* g_qx = (const float*)d_in[4];
    const float* b_qx = (const float*)d_in[5];
    const float* g_kx = (const float*)d_in[6];
    const float* b_kx = (const float*)d_in[7];
    const float* g_qa = (const float*)d_in[8];
    const float* b_qa = (const float*)d_in[9];
    const float* g_ka = (const float*)d_in[10];
    const float* b_ka = (const float*)d_in[11];
    float* out = (float*)d_out;

    const size_t E = (size_t)BB*NH*SEQ*DH;        // 4,194,304 elements
    float* wsq = (float*)d_ws;                    // 16MB
    float* wsk = wsq + E;                         // 16MB
    unsigned short* Vt = (unsigned short*)(wsk + E);  // 8MB
    unsigned short* region = Vt + E;              // dual-use
    unsigned short* Ab  = region;                 // 8MB (gemm phase)
    unsigned short* Qb  = region;                 // 8MB (attn phase, overlays Ab)
    unsigned short* Kb  = region + E;             // 8MB
    unsigned short* Bhi = region + 2*E;           // 3MB
    unsigned short* Blo = Bhi + (size_t)2*64*1536*8;  // 3MB
    float2* tab = (float2*)Bhi;                   // 512KB, reuses dead Bhi after GEMM

    prep_a<<<dim3(16, 64, 2), 256, 0, stream>>>(x, a, Ab);
    prep_b<<<dim3(6, 64, 2), 256, 0, stream>>>(Wx, Wa, Bhi, Blo);
    qkv_mfma<<<dim3(32, 12, 2), 256, 0, stream>>>(Ab, Bhi, Blo, wsq, wsk, Vt);
    rope_tab<<<dim3(256), 256, 0, stream>>>(tab);
    ln_rope<<<dim3(MROWS, 4), 512, 0, stream>>>(wsq, wsk, Qb, Kb, tab,
        g_qx, b_qx, g_kx, b_kx, g_qa, b_qa, g_ka, b_ka);
    attn_mfma<<<dim3(512), 256, 0, stream>>>(Qb, Kb, Vt, out);
}